// Round 3
// baseline (342.597 us; speedup 1.0000x reference)
//
#include <hip/hip_runtime.h>
#include <stdint.h>

typedef __bf16 bf16_t;
typedef __bf16 bf16x8 __attribute__((ext_vector_type(8)));
typedef __bf16 bf16x4 __attribute__((ext_vector_type(4)));
typedef float floatx4 __attribute__((ext_vector_type(4)));

#define AS3(p) ((__attribute__((address_space(3))) void*)(p))
#define AS1(p) ((__attribute__((address_space(1))) void*)(void*)(p))

// ---------- convert f32 -> bf16, flat ----------
__global__ __launch_bounds__(256) void cvt_k(const float* __restrict__ src,
                                             bf16_t* __restrict__ dst, int n) {
  const int i = (blockIdx.x * 256 + threadIdx.x) * 8;
  if (i + 8 <= n) {
    floatx4 a = *(const floatx4*)&src[i];
    floatx4 b = *(const floatx4*)&src[i + 4];
    bf16x8 o;
#pragma unroll
    for (int j = 0; j < 4; ++j) { o[j] = (bf16_t)a[j]; o[4 + j] = (bf16_t)b[j]; }
    *(bf16x8*)&dst[i] = o;
  }
}

// ---------- transpose + convert: dst[n][k] = (bf16)src[k][n]; src f32 [2048][ncols] ----------
__global__ __launch_bounds__(256) void tr_k(const float* __restrict__ src, int ncols,
                                            bf16_t* __restrict__ dst) {
  __shared__ __align__(16) bf16_t T[64][68];
  const int t = threadIdx.x;
  const int nt = blockIdx.x * 64, kt = blockIdx.y * 64;
  const int r0 = t >> 4;          // 0..15
  const int c0 = (t & 15) << 2;   // 0..60
#pragma unroll
  for (int p = 0; p < 4; ++p) {
    const int row = p * 16 + r0;
    floatx4 v = *(const floatx4*)&src[(size_t)(kt + row) * ncols + nt + c0];
    bf16x4 b;
#pragma unroll
    for (int i = 0; i < 4; ++i) b[i] = (bf16_t)v[i];
    *(bf16x4*)&T[row][c0] = b;
  }
  __syncthreads();
#pragma unroll
  for (int p = 0; p < 4; ++p) {
    const int n = p * 16 + r0;
    bf16x4 tmp;
#pragma unroll
    for (int i = 0; i < 4; ++i) tmp[i] = T[c0 + i][n];
    *(bf16x4*)&dst[(size_t)(nt + n) * 2048 + kt + c0] = tmp;
  }
}

// ---------- GEMM: C[m][n] = sum_k A[m][k] * Bt[n][k], K=2048, A/Bt bf16 ----------
// EPI 0: QKV epilogue (RoPE on q/k; v transposed-scatter with sigma-permuted
//        columns so the attention P^T B-fragment needs NO lane shuffles).
// EPI 1: plain f32 store to fo.
template <int EPI>
__global__ __launch_bounds__(256) void gemm_k(const bf16_t* __restrict__ A,
                                              const bf16_t* __restrict__ Bt,
                                              bf16_t* __restrict__ o0,
                                              bf16_t* __restrict__ o1,
                                              bf16_t* __restrict__ o2,
                                              float* __restrict__ fo,
                                              const float* __restrict__ fcos,
                                              const float* __restrict__ fsin) {
  constexpr int K = 2048;
  __shared__ __align__(16) bf16_t As[128 * 64];
  __shared__ __align__(16) bf16_t Bs[128 * 64];
  const int tid = threadIdx.x;
  const int lane = tid & 63;
  const int w = tid >> 6;
  const int quad = lane >> 4;
  const int l15 = lane & 15;
  const int m0 = blockIdx.y * 128;
  const int n0 = blockIdx.x * 128;
  const int wm = (w & 1) * 64;
  const int wn = (w >> 1) * 64;
  const int srow = lane >> 3;        // 0..7
  const int scol = (lane & 7) << 3;  // 0..56
  floatx4 acc[4][4] = {};

  for (int k0 = 0; k0 < K; k0 += 64) {
#pragma unroll
    for (int j = 0; j < 4; ++j) {
      const int row = j * 32 + w * 8 + srow;
      const bf16_t* ga = A + (size_t)(m0 + row) * K + k0 + scol;
      const bf16_t* gb = Bt + (size_t)(n0 + row) * K + k0 + scol;
      __builtin_amdgcn_global_load_lds(AS1(ga), AS3(&As[(j * 32 + w * 8) * 64]), 16, 0, 0);
      __builtin_amdgcn_global_load_lds(AS1(gb), AS3(&Bs[(j * 32 + w * 8) * 64]), 16, 0, 0);
    }
    __syncthreads();
#pragma unroll
    for (int kk = 0; kk < 2; ++kk) {
      bf16x8 af[4], bfr[4];
#pragma unroll
      for (int i = 0; i < 4; ++i) {
        af[i] = *(const bf16x8*)&As[(wm + i * 16 + l15) * 64 + kk * 32 + quad * 8];
        bfr[i] = *(const bf16x8*)&Bs[(wn + i * 16 + l15) * 64 + kk * 32 + quad * 8];
      }
#pragma unroll
      for (int mi = 0; mi < 4; ++mi)
#pragma unroll
        for (int ni = 0; ni < 4; ++ni)
          acc[mi][ni] =
              __builtin_amdgcn_mfma_f32_16x16x32_bf16(af[mi], bfr[ni], acc[mi][ni], 0, 0, 0);
    }
    __syncthreads();
  }

  if constexpr (EPI == 0) {
#pragma unroll
    for (int ni = 0; ni < 4; ++ni) {
      const int col = n0 + wn + ni * 16 + l15;
#pragma unroll
      for (int mi = 0; mi < 4; ++mi) {
        const int sb = m0 + wm + mi * 16 + quad * 4;
        if (col < 2560) {  // uniform per wave (boundaries are multiples of 16)
          const int fi = (col & 63) >> 1;
#pragma unroll
          for (int r = 0; r < 4; ++r) {
            const float v = acc[mi][ni][r];
            const float prt = __shfl_xor(v, 1);  // partner column within rope pair
            const int s = sb + r;
            const float c = fcos[s * 32 + fi];
            const float sn = fsin[s * 32 + fi];
            const float ov = (col & 1) ? (prt * sn + v * c) : (v * c - prt * sn);
            if (col < 2048)
              o0[(size_t)s * 2048 + col] = (bf16_t)ov;
            else
              o1[(size_t)s * 512 + (col - 2048)] = (bf16_t)ov;
          }
        } else {
          // sigma permutation within the 32-aligned s-block:
          // logical (t=mi&1, qs=quad, r) -> storage quad*8 + (mi&1)*4 + r
          const int sp = (sb & ~31) | (quad * 8 + (mi & 1) * 4);
          bf16x4 pv;
#pragma unroll
          for (int r = 0; r < 4; ++r) pv[r] = (bf16_t)acc[mi][ni][r];
          *(bf16x4*)&o2[(size_t)(col - 2560) * 2048 + sp] = pv;
        }
      }
    }
  } else {
#pragma unroll
    for (int ni = 0; ni < 4; ++ni) {
      const int col = n0 + wn + ni * 16 + l15;
#pragma unroll
      for (int mi = 0; mi < 4; ++mi) {
        const int sb = m0 + wm + mi * 16 + quad * 4;
#pragma unroll
        for (int r = 0; r < 4; ++r) fo[(size_t)(sb + r) * 2048 + col] = acc[mi][ni][r];
      }
    }
  }
}

// ---------- flash attention, S^T formulation, shuffle-free ----------
// qb_: [2048][2048]. kb_: [2048][512] (identity key order). vt_: [512][2048]
// (columns sigma-permuted per 32-block by gemm_k<0>). ob_: [2048][2048].
// Block = 64 queries x 1 head; wave = 16 queries, fully independent (no LDS).
__global__ __launch_bounds__(256) void attn_k(const bf16_t* __restrict__ qb_,
                                              const bf16_t* __restrict__ kb_,
                                              const bf16_t* __restrict__ vt_,
                                              bf16_t* __restrict__ ob_) {
  const int lane = threadIdx.x & 63, w = threadIdx.x >> 6;
  const int quad = lane >> 4, l15 = lane & 15;
  const int h = blockIdx.y, g = h >> 2;
  const int qb = (gridDim.x - 1 - blockIdx.x) * 64;  // heavy blocks first
  const int qw = qb + w * 16;
  const int q = qw + l15;
  const bf16_t* qrow = qb_ + (size_t)q * 2048 + h * 64;
  const bf16x8 qf0 = *(const bf16x8*)(qrow + quad * 8);
  const bf16x8 qf1 = *(const bf16x8*)(qrow + 32 + quad * 8);
  floatx4 acc[4] = {};
  floatx4 accl = {};
  const float SC = 0.125f * 1.44269504088896340736f;  // scale * log2(e)
  bf16x8 ones;
#pragma unroll
  for (int i = 0; i < 8; ++i) ones[i] = (bf16_t)1.0f;

  const int kend = qw + 16;
  int kb0 = qw - 1024;
  if (kb0 < 0) kb0 = 0;
  kb0 &= ~31;

  const bf16_t* kbase = kb_ + (size_t)l15 * 512 + g * 64 + quad * 8;
  const bf16_t* vbase = vt_ + (size_t)(g * 64 + l15) * 2048 + quad * 8;

  bf16x8 ka[4], va[4], kb2[4], vb2[4];

  auto ld = [&](bf16x8* kf, bf16x8* vf, int kb) {
    const bf16_t* kr = kbase + (size_t)kb * 512;
#pragma unroll
    for (int t = 0; t < 2; ++t) {
      kf[t * 2 + 0] = *(const bf16x8*)(kr + (size_t)t * 16 * 512);
      kf[t * 2 + 1] = *(const bf16x8*)(kr + (size_t)t * 16 * 512 + 32);
    }
    const bf16_t* vr = vbase + kb;
#pragma unroll
    for (int d = 0; d < 4; ++d) vf[d] = *(const bf16x8*)(vr + (size_t)d * 16 * 2048);
  };

  auto step = [&](const bf16x8* kf, const bf16x8* vf, int kb) {
    floatx4 z0 = {}, z1 = {};
    z0 = __builtin_amdgcn_mfma_f32_16x16x32_bf16(kf[0], qf0, z0, 0, 0, 0);
    z0 = __builtin_amdgcn_mfma_f32_16x16x32_bf16(kf[1], qf1, z0, 0, 0, 0);
    z1 = __builtin_amdgcn_mfma_f32_16x16x32_bf16(kf[2], qf0, z1, 0, 0, 0);
    z1 = __builtin_amdgcn_mfma_f32_16x16x32_bf16(kf[3], qf1, z1, 0, 0, 0);
    float p[8];
#pragma unroll
    for (int r = 0; r < 4; ++r) {
      p[r] = z0[r] * SC - 32.0f;       // fixed softmax offset (2^-32 cancels in p/l)
      p[4 + r] = z1[r] * SC - 32.0f;
    }
    if ((kb + 31 > qw) || (kb < qw - 1009)) {  // wave-uniform edge mask
#pragma unroll
      for (int t = 0; t < 2; ++t)
#pragma unroll
        for (int r = 0; r < 4; ++r) {
          const int key = kb + t * 16 + quad * 4 + r;
          if (key > q || key + 1024 < q) p[t * 4 + r] = -1.0e30f;
        }
    }
    bf16x8 pf;  // == P^T B-fragment directly (sigma-permuted V columns)
#pragma unroll
    for (int i = 0; i < 8; ++i) pf[i] = (bf16_t)__builtin_amdgcn_exp2f(p[i]);
    accl = __builtin_amdgcn_mfma_f32_16x16x32_bf16(ones, pf, accl, 0, 0, 0);
#pragma unroll
    for (int d = 0; d < 4; ++d)
      acc[d] = __builtin_amdgcn_mfma_f32_16x16x32_bf16(vf[d], pf, acc[d], 0, 0, 0);
  };

  int kb = kb0;
  ld(ka, va, kb);
  while (true) {
    int nx = kb + 32;
    bool last = nx >= kend;
    ld(kb2, vb2, last ? kb : nx);  // prefetch (clamped when last)
    step(ka, va, kb);
    if (last) break;
    kb = nx;
    nx = kb + 32;
    last = nx >= kend;
    ld(ka, va, last ? kb : nx);
    step(kb2, vb2, kb);
    if (last) break;
    kb = nx;
  }

  const float inv = 1.0f / accl[0];
#pragma unroll
  for (int d = 0; d < 4; ++d) {
    bf16x4 ov;
#pragma unroll
    for (int r = 0; r < 4; ++r) ov[r] = (bf16_t)(acc[d][r] * inv);
    *(bf16x4*)&ob_[(size_t)q * 2048 + h * 64 + d * 16 + quad * 4] = ov;
  }
}

extern "C" void kernel_launch(void* const* d_in, const int* in_sizes, int n_in, void* d_out,
                              int out_size, void* d_ws, size_t ws_size, hipStream_t stream) {
  (void)in_sizes;
  (void)n_in;
  (void)out_size;
  (void)ws_size;
  const float* x = (const float*)d_in[0];
  const float* wq = (const float*)d_in[1];
  const float* wk = (const float*)d_in[2];
  const float* wv = (const float*)d_in[3];
  const float* wo = (const float*)d_in[4];
  const float* fcos = (const float*)d_in[5];
  const float* fsin = (const float*)d_in[6];
  float* out = (float*)d_out;

  bf16_t* xb = (bf16_t*)d_ws;
  bf16_t* wt = xb + (size_t)2048 * 2048;
  bf16_t* qbuf = wt + (size_t)5120 * 2048;
  bf16_t* kbuf = qbuf + (size_t)2048 * 2048;
  bf16_t* vtb = kbuf + (size_t)2048 * 512;
  bf16_t* att = vtb + (size_t)512 * 2048;

  cvt_k<<<2048, 256, 0, stream>>>(x, xb, 2048 * 2048);
  tr_k<<<dim3(32, 32), 256, 0, stream>>>(wq, 2048, wt);
  tr_k<<<dim3(8, 32), 256, 0, stream>>>(wk, 512, wt + (size_t)2048 * 2048);
  tr_k<<<dim3(8, 32), 256, 0, stream>>>(wv, 512, wt + (size_t)2560 * 2048);
  tr_k<<<dim3(32, 32), 256, 0, stream>>>(wo, 2048, wt + (size_t)3072 * 2048);
  gemm_k<0><<<dim3(24, 16), 256, 0, stream>>>(xb, wt, qbuf, kbuf, vtb, nullptr, fcos, fsin);
  attn_k<<<dim3(32, 32), 256, 0, stream>>>(qbuf, kbuf, vtb, att);
  gemm_k<1><<<dim3(16, 16), 256, 0, stream>>>(att, wt + (size_t)3072 * 2048, nullptr, nullptr,
                                              nullptr, out, fcos, fsin);
}

// Round 4
// 338.954 us; speedup vs baseline: 1.0107x; 1.0107x over previous
//
#include <hip/hip_runtime.h>
#include <stdint.h>

typedef __bf16 bf16_t;
typedef __bf16 bf16x8 __attribute__((ext_vector_type(8)));
typedef __bf16 bf16x4 __attribute__((ext_vector_type(4)));
typedef float floatx4 __attribute__((ext_vector_type(4)));

#define AS3(p) ((__attribute__((address_space(3))) void*)(p))
#define AS1(p) ((__attribute__((address_space(1))) void*)(void*)(p))

// ---------- convert f32 -> bf16, flat ----------
__global__ __launch_bounds__(256) void cvt_k(const float* __restrict__ src,
                                             bf16_t* __restrict__ dst, int n) {
  const int i = (blockIdx.x * 256 + threadIdx.x) * 8;
  if (i + 8 <= n) {
    floatx4 a = *(const floatx4*)&src[i];
    floatx4 b = *(const floatx4*)&src[i + 4];
    bf16x8 o;
#pragma unroll
    for (int j = 0; j < 4; ++j) { o[j] = (bf16_t)a[j]; o[4 + j] = (bf16_t)b[j]; }
    *(bf16x8*)&dst[i] = o;
  }
}

// ---------- transpose + convert: dst[n][k] = (bf16)src[k][n]; src f32 [2048][ncols] ----------
__global__ __launch_bounds__(256) void tr_k(const float* __restrict__ src, int ncols,
                                            bf16_t* __restrict__ dst) {
  __shared__ __align__(16) bf16_t T[64][68];
  const int t = threadIdx.x;
  const int nt = blockIdx.x * 64, kt = blockIdx.y * 64;
  const int r0 = t >> 4;          // 0..15
  const int c0 = (t & 15) << 2;   // 0..60
#pragma unroll
  for (int p = 0; p < 4; ++p) {
    const int row = p * 16 + r0;
    floatx4 v = *(const floatx4*)&src[(size_t)(kt + row) * ncols + nt + c0];
    bf16x4 b;
#pragma unroll
    for (int i = 0; i < 4; ++i) b[i] = (bf16_t)v[i];
    *(bf16x4*)&T[row][c0] = b;
  }
  __syncthreads();
#pragma unroll
  for (int p = 0; p < 4; ++p) {
    const int n = p * 16 + r0;
    bf16x4 tmp;
#pragma unroll
    for (int i = 0; i < 4; ++i) tmp[i] = T[c0 + i][n];
    *(bf16x4*)&dst[(size_t)(nt + n) * 2048 + kt + c0] = tmp;
  }
}

// ---------- GEMM: C[m][n] = sum_k A[m][k] * Bt[n][k], K=2048, A/Bt bf16 ----------
template <int EPI>
__global__ __launch_bounds__(256) void gemm_k(const bf16_t* __restrict__ A,
                                              const bf16_t* __restrict__ Bt,
                                              bf16_t* __restrict__ o0,
                                              bf16_t* __restrict__ o1,
                                              bf16_t* __restrict__ o2,
                                              float* __restrict__ fo,
                                              const float* __restrict__ fcos,
                                              const float* __restrict__ fsin) {
  constexpr int K = 2048;
  __shared__ __align__(16) bf16_t As[128 * 64];
  __shared__ __align__(16) bf16_t Bs[128 * 64];
  const int tid = threadIdx.x;
  const int lane = tid & 63;
  const int w = tid >> 6;
  const int quad = lane >> 4;
  const int l15 = lane & 15;
  const int m0 = blockIdx.y * 128;
  const int n0 = blockIdx.x * 128;
  const int wm = (w & 1) * 64;
  const int wn = (w >> 1) * 64;
  const int srow = lane >> 3;        // 0..7
  const int scol = (lane & 7) << 3;  // 0..56
  floatx4 acc[4][4] = {};

  for (int k0 = 0; k0 < K; k0 += 64) {
#pragma unroll
    for (int j = 0; j < 4; ++j) {
      const int row = j * 32 + w * 8 + srow;
      const bf16_t* ga = A + (size_t)(m0 + row) * K + k0 + scol;
      const bf16_t* gb = Bt + (size_t)(n0 + row) * K + k0 + scol;
      __builtin_amdgcn_global_load_lds(AS1(ga), AS3(&As[(j * 32 + w * 8) * 64]), 16, 0, 0);
      __builtin_amdgcn_global_load_lds(AS1(gb), AS3(&Bs[(j * 32 + w * 8) * 64]), 16, 0, 0);
    }
    __syncthreads();
#pragma unroll
    for (int kk = 0; kk < 2; ++kk) {
      bf16x8 af[4], bfr[4];
#pragma unroll
      for (int i = 0; i < 4; ++i) {
        af[i] = *(const bf16x8*)&As[(wm + i * 16 + l15) * 64 + kk * 32 + quad * 8];
        bfr[i] = *(const bf16x8*)&Bs[(wn + i * 16 + l15) * 64 + kk * 32 + quad * 8];
      }
#pragma unroll
      for (int mi = 0; mi < 4; ++mi)
#pragma unroll
        for (int ni = 0; ni < 4; ++ni)
          acc[mi][ni] =
              __builtin_amdgcn_mfma_f32_16x16x32_bf16(af[mi], bfr[ni], acc[mi][ni], 0, 0, 0);
    }
    __syncthreads();
  }

  if constexpr (EPI == 0) {
#pragma unroll
    for (int ni = 0; ni < 4; ++ni) {
      const int col = n0 + wn + ni * 16 + l15;
#pragma unroll
      for (int mi = 0; mi < 4; ++mi) {
        const int sb = m0 + wm + mi * 16 + quad * 4;
        if (col < 2560) {  // uniform per wave (boundaries are multiples of 16)
          const int fi = (col & 63) >> 1;
#pragma unroll
          for (int r = 0; r < 4; ++r) {
            const float v = acc[mi][ni][r];
            const float prt = __shfl_xor(v, 1);  // partner column within rope pair
            const int s = sb + r;
            const float c = fcos[s * 32 + fi];
            const float sn = fsin[s * 32 + fi];
            const float ov = (col & 1) ? (prt * sn + v * c) : (v * c - prt * sn);
            if (col < 2048)
              o0[(size_t)s * 2048 + col] = (bf16_t)ov;
            else
              o1[(size_t)s * 512 + (col - 2048)] = (bf16_t)ov;
          }
        } else {
          // sigma permutation within the 32-aligned s-block:
          // logical (t=mi&1, qs=quad, r) -> storage quad*8 + (mi&1)*4 + r
          const int sp = (sb & ~31) | (quad * 8 + (mi & 1) * 4);
          bf16x4 pv;
#pragma unroll
          for (int r = 0; r < 4; ++r) pv[r] = (bf16_t)acc[mi][ni][r];
          *(bf16x4*)&o2[(size_t)(col - 2560) * 2048 + sp] = pv;
        }
      }
    }
  } else {
#pragma unroll
    for (int ni = 0; ni < 4; ++ni) {
      const int col = n0 + wn + ni * 16 + l15;
#pragma unroll
      for (int mi = 0; mi < 4; ++mi) {
        const int sb = m0 + wm + mi * 16 + quad * 4;
#pragma unroll
        for (int r = 0; r < 4; ++r) fo[(size_t)(sb + r) * 2048 + col] = acc[mi][ni][r];
      }
    }
  }
}

// ---------- flash attention, S^T formulation, shuffle-free, array/lambda-free ----------
// qb_: [2048][2048]. kb_: [2048][512]. vt_: [512][2048] (sigma-permuted cols).
// ob_: [2048][2048]. Block = 64 queries x 1 head; wave = 16 queries.
// All fragment state in NAMED registers (R3's array-through-lambda form spilled to
// scratch: VGPR_Count=64 vs >100 live — this rewrite keeps everything in VGPRs).
__global__ __launch_bounds__(256, 4) void attn_k(const bf16_t* __restrict__ qb_,
                                                 const bf16_t* __restrict__ kb_,
                                                 const bf16_t* __restrict__ vt_,
                                                 bf16_t* __restrict__ ob_) {
  const int lane = threadIdx.x & 63, w = threadIdx.x >> 6;
  const int quad = lane >> 4, l15 = lane & 15;
  const int h = blockIdx.y, g = h >> 2;
  const int qb = (gridDim.x - 1 - blockIdx.x) * 64;  // heavy blocks first
  const int qw = qb + w * 16;
  const int q = qw + l15;
  const bf16_t* qrow = qb_ + (size_t)q * 2048 + h * 64;
  const bf16x8 qf0 = *(const bf16x8*)(qrow + quad * 8);
  const bf16x8 qf1 = *(const bf16x8*)(qrow + 32 + quad * 8);
  floatx4 acc0 = {}, acc1 = {}, acc2 = {}, acc3 = {}, accl = {};
  const float SC = 0.125f * 1.44269504088896340736f;  // scale * log2(e)
  bf16x8 ones;
#pragma unroll
  for (int i = 0; i < 8; ++i) ones[i] = (bf16_t)1.0f;

  const int kend = qw + 16;
  int kb0 = qw - 1024;
  if (kb0 < 0) kb0 = 0;
  kb0 &= ~31;

  const bf16_t* kbase = kb_ + (size_t)l15 * 512 + g * 64 + quad * 8;
  const bf16_t* vbase = vt_ + (size_t)(g * 64 + l15) * 2048 + quad * 8;

  bf16x8 k0a, k1a, k2a, k3a, v0a, v1a, v2a, v3a;
  bf16x8 k0b, k1b, k2b, k3b, v0b, v1b, v2b, v3b;

#define LD(S, kbv)                                          \
  do {                                                      \
    const bf16_t* kr_ = kbase + (size_t)(kbv) * 512;        \
    const bf16_t* vr_ = vbase + (kbv);                      \
    k0##S = *(const bf16x8*)(kr_);                          \
    k1##S = *(const bf16x8*)(kr_ + 32);                     \
    k2##S = *(const bf16x8*)(kr_ + 16 * 512);               \
    k3##S = *(const bf16x8*)(kr_ + 16 * 512 + 32);          \
    v0##S = *(const bf16x8*)(vr_);                          \
    v1##S = *(const bf16x8*)(vr_ + 16 * 2048);              \
    v2##S = *(const bf16x8*)(vr_ + 32 * 2048);              \
    v3##S = *(const bf16x8*)(vr_ + 48 * 2048);              \
  } while (0)

#define MSK(pv, key)                                        \
  do {                                                      \
    if ((key) > q || (key) + 1024 < q) pv = -1.0e30f;       \
  } while (0)

#define STEP(S, kbv)                                                               \
  do {                                                                             \
    floatx4 z0 = {}, z1 = {};                                                      \
    z0 = __builtin_amdgcn_mfma_f32_16x16x32_bf16(k0##S, qf0, z0, 0, 0, 0);         \
    z0 = __builtin_amdgcn_mfma_f32_16x16x32_bf16(k1##S, qf1, z0, 0, 0, 0);         \
    z1 = __builtin_amdgcn_mfma_f32_16x16x32_bf16(k2##S, qf0, z1, 0, 0, 0);         \
    z1 = __builtin_amdgcn_mfma_f32_16x16x32_bf16(k3##S, qf1, z1, 0, 0, 0);         \
    float p0 = z0[0] * SC - 32.0f, p1 = z0[1] * SC - 32.0f;                        \
    float p2 = z0[2] * SC - 32.0f, p3 = z0[3] * SC - 32.0f;                        \
    float p4 = z1[0] * SC - 32.0f, p5 = z1[1] * SC - 32.0f;                        \
    float p6 = z1[2] * SC - 32.0f, p7 = z1[3] * SC - 32.0f;                        \
    if (((kbv) + 31 > qw) || ((kbv) < qw - 1009)) {                                \
      const int kq = (kbv) + quad * 4;                                             \
      MSK(p0, kq + 0); MSK(p1, kq + 1); MSK(p2, kq + 2); MSK(p3, kq + 3);          \
      MSK(p4, kq + 16); MSK(p5, kq + 17); MSK(p6, kq + 18); MSK(p7, kq + 19);      \
    }                                                                              \
    bf16x8 pf;                                                                     \
    pf[0] = (bf16_t)__builtin_amdgcn_exp2f(p0);                                    \
    pf[1] = (bf16_t)__builtin_amdgcn_exp2f(p1);                                    \
    pf[2] = (bf16_t)__builtin_amdgcn_exp2f(p2);                                    \
    pf[3] = (bf16_t)__builtin_amdgcn_exp2f(p3);                                    \
    pf[4] = (bf16_t)__builtin_amdgcn_exp2f(p4);                                    \
    pf[5] = (bf16_t)__builtin_amdgcn_exp2f(p5);                                    \
    pf[6] = (bf16_t)__builtin_amdgcn_exp2f(p6);                                    \
    pf[7] = (bf16_t)__builtin_amdgcn_exp2f(p7);                                    \
    accl = __builtin_amdgcn_mfma_f32_16x16x32_bf16(ones, pf, accl, 0, 0, 0);       \
    acc0 = __builtin_amdgcn_mfma_f32_16x16x32_bf16(v0##S, pf, acc0, 0, 0, 0);      \
    acc1 = __builtin_amdgcn_mfma_f32_16x16x32_bf16(v1##S, pf, acc1, 0, 0, 0);      \
    acc2 = __builtin_amdgcn_mfma_f32_16x16x32_bf16(v2##S, pf, acc2, 0, 0, 0);      \
    acc3 = __builtin_amdgcn_mfma_f32_16x16x32_bf16(v3##S, pf, acc3, 0, 0, 0);      \
  } while (0)

  int kb = kb0;
  int nx = kb + 32;
  LD(a, kb);
  while (true) {
    bool last = nx >= kend;
    LD(b, last ? kb : nx);
    STEP(a, kb);
    if (last) break;
    kb = nx;
    nx += 32;
    last = nx >= kend;
    LD(a, last ? kb : nx);
    STEP(b, kb);
    if (last) break;
    kb = nx;
    nx += 32;
  }
#undef LD
#undef MSK
#undef STEP

  const float inv = 1.0f / accl[0];
  bf16_t* obase = ob_ + (size_t)q * 2048 + h * 64 + quad * 4;
  bf16x4 ov;
#pragma unroll
  for (int r = 0; r < 4; ++r) ov[r] = (bf16_t)(acc0[r] * inv);
  *(bf16x4*)(obase) = ov;
#pragma unroll
  for (int r = 0; r < 4; ++r) ov[r] = (bf16_t)(acc1[r] * inv);
  *(bf16x4*)(obase + 16) = ov;
#pragma unroll
  for (int r = 0; r < 4; ++r) ov[r] = (bf16_t)(acc2[r] * inv);
  *(bf16x4*)(obase + 32) = ov;
#pragma unroll
  for (int r = 0; r < 4; ++r) ov[r] = (bf16_t)(acc3[r] * inv);
  *(bf16x4*)(obase + 48) = ov;
}

extern "C" void kernel_launch(void* const* d_in, const int* in_sizes, int n_in, void* d_out,
                              int out_size, void* d_ws, size_t ws_size, hipStream_t stream) {
  (void)in_sizes;
  (void)n_in;
  (void)out_size;
  (void)ws_size;
  const float* x = (const float*)d_in[0];
  const float* wq = (const float*)d_in[1];
  const float* wk = (const float*)d_in[2];
  const float* wv = (const float*)d_in[3];
  const float* wo = (const float*)d_in[4];
  const float* fcos = (const float*)d_in[5];
  const float* fsin = (const float*)d_in[6];
  float* out = (float*)d_out;

  bf16_t* xb = (bf16_t*)d_ws;
  bf16_t* wt = xb + (size_t)2048 * 2048;
  bf16_t* qbuf = wt + (size_t)5120 * 2048;
  bf16_t* kbuf = qbuf + (size_t)2048 * 2048;
  bf16_t* vtb = kbuf + (size_t)2048 * 512;
  bf16_t* att = vtb + (size_t)512 * 2048;

  cvt_k<<<2048, 256, 0, stream>>>(x, xb, 2048 * 2048);
  tr_k<<<dim3(32, 32), 256, 0, stream>>>(wq, 2048, wt);
  tr_k<<<dim3(8, 32), 256, 0, stream>>>(wk, 512, wt + (size_t)2048 * 2048);
  tr_k<<<dim3(8, 32), 256, 0, stream>>>(wv, 512, wt + (size_t)2560 * 2048);
  tr_k<<<dim3(32, 32), 256, 0, stream>>>(wo, 2048, wt + (size_t)3072 * 2048);
  gemm_k<0><<<dim3(24, 16), 256, 0, stream>>>(xb, wt, qbuf, kbuf, vtb, nullptr, fcos, fsin);
  attn_k<<<dim3(32, 32), 256, 0, stream>>>(qbuf, kbuf, vtb, att);
  gemm_k<1><<<dim3(16, 16), 256, 0, stream>>>(att, wt + (size_t)3072 * 2048, nullptr, nullptr,
                                              nullptr, out, fcos, fsin);
}

// Round 5
// 256.648 us; speedup vs baseline: 1.3349x; 1.3207x over previous
//
#include <hip/hip_runtime.h>
#include <stdint.h>

typedef __bf16 bf16_t;
typedef __bf16 bf16x8 __attribute__((ext_vector_type(8)));
typedef __bf16 bf16x4 __attribute__((ext_vector_type(4)));
typedef float floatx4 __attribute__((ext_vector_type(4)));

#define AS3(p) ((__attribute__((address_space(3))) void*)(p))
#define AS1(p) ((__attribute__((address_space(1))) void*)(void*)(p))

// ---------- convert f32 -> bf16, flat ----------
__global__ __launch_bounds__(256) void cvt_k(const float* __restrict__ src,
                                             bf16_t* __restrict__ dst, int n) {
  const int i = (blockIdx.x * 256 + threadIdx.x) * 8;
  if (i + 8 <= n) {
    floatx4 a = *(const floatx4*)&src[i];
    floatx4 b = *(const floatx4*)&src[i + 4];
    bf16x8 o;
#pragma unroll
    for (int j = 0; j < 4; ++j) { o[j] = (bf16_t)a[j]; o[4 + j] = (bf16_t)b[j]; }
    *(bf16x8*)&dst[i] = o;
  }
}

// ---------- transpose + convert: dst[n][k] = (bf16)src[k][n]; src f32 [2048][ncols] ----------
__global__ __launch_bounds__(256) void tr_k(const float* __restrict__ src, int ncols,
                                            bf16_t* __restrict__ dst) {
  __shared__ __align__(16) bf16_t T[64][68];
  const int t = threadIdx.x;
  const int nt = blockIdx.x * 64, kt = blockIdx.y * 64;
  const int r0 = t >> 4;          // 0..15
  const int c0 = (t & 15) << 2;   // 0..60
#pragma unroll
  for (int p = 0; p < 4; ++p) {
    const int row = p * 16 + r0;
    floatx4 v = *(const floatx4*)&src[(size_t)(kt + row) * ncols + nt + c0];
    bf16x4 b;
#pragma unroll
    for (int i = 0; i < 4; ++i) b[i] = (bf16_t)v[i];
    *(bf16x4*)&T[row][c0] = b;
  }
  __syncthreads();
#pragma unroll
  for (int p = 0; p < 4; ++p) {
    const int n = p * 16 + r0;
    bf16x4 tmp;
#pragma unroll
    for (int i = 0; i < 4; ++i) tmp[i] = T[c0 + i][n];
    *(bf16x4*)&dst[(size_t)(nt + n) * 2048 + kt + c0] = tmp;
  }
}

// ---------- GEMM: C[m][n] = sum_k A[m][k] * Bt[n][k], K=2048, A/Bt bf16 ----------
template <int EPI>
__global__ __launch_bounds__(256) void gemm_k(const bf16_t* __restrict__ A,
                                              const bf16_t* __restrict__ Bt,
                                              bf16_t* __restrict__ o0,
                                              bf16_t* __restrict__ o1,
                                              bf16_t* __restrict__ o2,
                                              float* __restrict__ fo,
                                              const float* __restrict__ fcos,
                                              const float* __restrict__ fsin) {
  constexpr int K = 2048;
  __shared__ __align__(16) bf16_t As[128 * 64];
  __shared__ __align__(16) bf16_t Bs[128 * 64];
  const int tid = threadIdx.x;
  const int lane = tid & 63;
  const int w = tid >> 6;
  const int quad = lane >> 4;
  const int l15 = lane & 15;
  const int m0 = blockIdx.y * 128;
  const int n0 = blockIdx.x * 128;
  const int wm = (w & 1) * 64;
  const int wn = (w >> 1) * 64;
  const int srow = lane >> 3;        // 0..7
  const int scol = (lane & 7) << 3;  // 0..56
  floatx4 acc[4][4] = {};

  for (int k0 = 0; k0 < K; k0 += 64) {
#pragma unroll
    for (int j = 0; j < 4; ++j) {
      const int row = j * 32 + w * 8 + srow;
      const bf16_t* ga = A + (size_t)(m0 + row) * K + k0 + scol;
      const bf16_t* gb = Bt + (size_t)(n0 + row) * K + k0 + scol;
      __builtin_amdgcn_global_load_lds(AS1(ga), AS3(&As[(j * 32 + w * 8) * 64]), 16, 0, 0);
      __builtin_amdgcn_global_load_lds(AS1(gb), AS3(&Bs[(j * 32 + w * 8) * 64]), 16, 0, 0);
    }
    __syncthreads();
#pragma unroll
    for (int kk = 0; kk < 2; ++kk) {
      bf16x8 af[4], bfr[4];
#pragma unroll
      for (int i = 0; i < 4; ++i) {
        af[i] = *(const bf16x8*)&As[(wm + i * 16 + l15) * 64 + kk * 32 + quad * 8];
        bfr[i] = *(const bf16x8*)&Bs[(wn + i * 16 + l15) * 64 + kk * 32 + quad * 8];
      }
#pragma unroll
      for (int mi = 0; mi < 4; ++mi)
#pragma unroll
        for (int ni = 0; ni < 4; ++ni)
          acc[mi][ni] =
              __builtin_amdgcn_mfma_f32_16x16x32_bf16(af[mi], bfr[ni], acc[mi][ni], 0, 0, 0);
    }
    __syncthreads();
  }

  if constexpr (EPI == 0) {
#pragma unroll
    for (int ni = 0; ni < 4; ++ni) {
      const int col = n0 + wn + ni * 16 + l15;
#pragma unroll
      for (int mi = 0; mi < 4; ++mi) {
        const int sb = m0 + wm + mi * 16 + quad * 4;
        if (col < 2560) {  // uniform per wave (boundaries are multiples of 16)
          const int fi = (col & 63) >> 1;
#pragma unroll
          for (int r = 0; r < 4; ++r) {
            const float v = acc[mi][ni][r];
            const float prt = __shfl_xor(v, 1);  // partner column within rope pair
            const int s = sb + r;
            const float c = fcos[s * 32 + fi];
            const float sn = fsin[s * 32 + fi];
            const float ov = (col & 1) ? (prt * sn + v * c) : (v * c - prt * sn);
            if (col < 2048)
              o0[(size_t)s * 2048 + col] = (bf16_t)ov;
            else
              o1[(size_t)s * 512 + (col - 2048)] = (bf16_t)ov;
          }
        } else {
          // sigma permutation within the 32-aligned s-block:
          // logical (t=mi&1, qs=quad, r) -> storage quad*8 + (mi&1)*4 + r
          const int sp = (sb & ~31) | (quad * 8 + (mi & 1) * 4);
          bf16x4 pv;
#pragma unroll
          for (int r = 0; r < 4; ++r) pv[r] = (bf16_t)acc[mi][ni][r];
          *(bf16x4*)&o2[(size_t)(col - 2560) * 2048 + sp] = pv;
        }
      }
    }
  } else {
#pragma unroll
    for (int ni = 0; ni < 4; ++ni) {
      const int col = n0 + wn + ni * 16 + l15;
#pragma unroll
      for (int mi = 0; mi < 4; ++mi) {
        const int sb = m0 + wm + mi * 16 + quad * 4;
#pragma unroll
        for (int r = 0; r < 4; ++r) fo[(size_t)(sb + r) * 2048 + col] = acc[mi][ni][r];
      }
    }
  }
}

// ---------- flash attention, S^T formulation, LDS-staged K/V ----------
// qb_: [2048][2048]. kb_: [2048][512]. vt_: [512][2048] (sigma-permuted cols).
// ob_: [2048][2048]. Block = 64 queries x 1 head; 4 waves share the K/V tile.
// K/V staged via global_load_lds in FRAGMENT-READ ORDER (LDS slot = reading
// lane), so compute-side ds_read_b128 is lane-linear (2-way = free) and the
// prefetch is DMA-based — the compiler cannot sink it (R3/R4 failure mode:
// per-lane register prefetch got re-sunk to load-before-use, serializing on
// memory latency; MfmaUtil 4.5%).
__global__ __launch_bounds__(256) void attn_k(const bf16_t* __restrict__ qb_,
                                              const bf16_t* __restrict__ kb_,
                                              const bf16_t* __restrict__ vt_,
                                              bf16_t* __restrict__ ob_) {
  // 2 buffers x 8 regions x 512 bf16 (1 KB each): regions 0-3 = K frags
  // (t*2+chunkhalf), 4-7 = V frags (d). 16 KB total.
  __shared__ __align__(16) bf16_t sm[2][8 * 512];
  const int lane = threadIdx.x & 63, w = threadIdx.x >> 6;
  const int quad = lane >> 4, l15 = lane & 15;
  const int h = blockIdx.y, g = h >> 2;
  const int qb = (gridDim.x - 1 - blockIdx.x) * 64;  // heavy blocks first
  const int qw = qb + w * 16;
  const int q = qw + l15;
  const bf16_t* qrow = qb_ + (size_t)q * 2048 + h * 64;
  const bf16x8 qf0 = *(const bf16x8*)(qrow + quad * 8);
  const bf16x8 qf1 = *(const bf16x8*)(qrow + 32 + quad * 8);
  floatx4 acc0 = {}, acc1 = {}, acc2 = {}, acc3 = {}, accl = {};
  const float SC = 0.125f * 1.44269504088896340736f;  // scale * log2(e)
  bf16x8 ones;
#pragma unroll
  for (int i = 0; i < 8; ++i) ones[i] = (bf16_t)1.0f;

  int kbB = qb - 1024;
  if (kbB < 0) kbB = 0;
  kbB &= ~31;
  const int nT = (qb + 64 - kbB) >> 5;  // block-level tile count
  int myS = qw - 1024;
  if (myS < 0) myS = 0;
  myS &= ~31;                 // this wave's first tile
  const int myE = qw + 16;    // this wave's end (exclusive)

  // Staging sources. Wave w stages K region w and V region w.
  // K region w covers (row = (w>>1)*16 + (lane&15), dim chunk = (w&1)*4 + (lane>>4)).
  // V region w covers (dim row = w*16 + (lane&15), key chunk = lane>>4).
  const int lr = lane & 15, lc = lane >> 4;
  const bf16_t* gk = kb_ + (size_t)(kbB + (w >> 1) * 16 + lr) * 512 + g * 64 +
                     ((w & 1) * 4 + lc) * 8;
  const bf16_t* gv = vt_ + (size_t)(g * 64 + w * 16 + lr) * 2048 + kbB + lc * 8;

#define STAGE(bi, ti)                                                              \
  do {                                                                             \
    __builtin_amdgcn_global_load_lds(AS1(gk + (size_t)(ti) * (32 * 512)),          \
                                     AS3(&sm[bi][w * 512]), 16, 0, 0);             \
    __builtin_amdgcn_global_load_lds(AS1(gv + (size_t)(ti) * 32),                  \
                                     AS3(&sm[bi][(4 + w) * 512]), 16, 0, 0);       \
  } while (0)

#define MSK(pv, key)                                        \
  do {                                                      \
    if ((key) > q || (key) + 1024 < q) pv = -1.0e30f;       \
  } while (0)

  int kb = kbB;
  STAGE(0, 0);
  __syncthreads();
  for (int i = 0; i < nT; ++i, kb += 32) {
    if (i + 1 < nT) STAGE((i + 1) & 1, i + 1);
    if (kb >= myS && kb < myE) {  // wave-uniform
      const bf16_t* base = &sm[i & 1][(size_t)lane * 8];
      const bf16x8 k0 = *(const bf16x8*)(base);
      const bf16x8 k1 = *(const bf16x8*)(base + 512);
      const bf16x8 k2 = *(const bf16x8*)(base + 1024);
      const bf16x8 k3 = *(const bf16x8*)(base + 1536);
      const bf16x8 v0 = *(const bf16x8*)(base + 2048);
      const bf16x8 v1 = *(const bf16x8*)(base + 2560);
      const bf16x8 v2 = *(const bf16x8*)(base + 3072);
      const bf16x8 v3 = *(const bf16x8*)(base + 3584);
      floatx4 z0 = {}, z1 = {};
      z0 = __builtin_amdgcn_mfma_f32_16x16x32_bf16(k0, qf0, z0, 0, 0, 0);
      z0 = __builtin_amdgcn_mfma_f32_16x16x32_bf16(k1, qf1, z0, 0, 0, 0);
      z1 = __builtin_amdgcn_mfma_f32_16x16x32_bf16(k2, qf0, z1, 0, 0, 0);
      z1 = __builtin_amdgcn_mfma_f32_16x16x32_bf16(k3, qf1, z1, 0, 0, 0);
      float p0 = z0[0] * SC - 32.0f, p1 = z0[1] * SC - 32.0f;
      float p2 = z0[2] * SC - 32.0f, p3 = z0[3] * SC - 32.0f;
      float p4 = z1[0] * SC - 32.0f, p5 = z1[1] * SC - 32.0f;
      float p6 = z1[2] * SC - 32.0f, p7 = z1[3] * SC - 32.0f;
      if ((kb + 31 > qw) || (kb < qw - 1009)) {  // wave-uniform edge mask
        const int kq = kb + quad * 4;
        MSK(p0, kq + 0); MSK(p1, kq + 1); MSK(p2, kq + 2); MSK(p3, kq + 3);
        MSK(p4, kq + 16); MSK(p5, kq + 17); MSK(p6, kq + 18); MSK(p7, kq + 19);
      }
      bf16x8 pf;  // == P^T B-fragment directly (sigma-permuted V columns)
      pf[0] = (bf16_t)__builtin_amdgcn_exp2f(p0);
      pf[1] = (bf16_t)__builtin_amdgcn_exp2f(p1);
      pf[2] = (bf16_t)__builtin_amdgcn_exp2f(p2);
      pf[3] = (bf16_t)__builtin_amdgcn_exp2f(p3);
      pf[4] = (bf16_t)__builtin_amdgcn_exp2f(p4);
      pf[5] = (bf16_t)__builtin_amdgcn_exp2f(p5);
      pf[6] = (bf16_t)__builtin_amdgcn_exp2f(p6);
      pf[7] = (bf16_t)__builtin_amdgcn_exp2f(p7);
      accl = __builtin_amdgcn_mfma_f32_16x16x32_bf16(ones, pf, accl, 0, 0, 0);
      acc0 = __builtin_amdgcn_mfma_f32_16x16x32_bf16(v0, pf, acc0, 0, 0, 0);
      acc1 = __builtin_amdgcn_mfma_f32_16x16x32_bf16(v1, pf, acc1, 0, 0, 0);
      acc2 = __builtin_amdgcn_mfma_f32_16x16x32_bf16(v2, pf, acc2, 0, 0, 0);
      acc3 = __builtin_amdgcn_mfma_f32_16x16x32_bf16(v3, pf, acc3, 0, 0, 0);
    }
    __syncthreads();
  }
#undef STAGE
#undef MSK

  const float inv = 1.0f / accl[0];
  bf16_t* obase = ob_ + (size_t)q * 2048 + h * 64 + quad * 4;
  bf16x4 ov;
#pragma unroll
  for (int r = 0; r < 4; ++r) ov[r] = (bf16_t)(acc0[r] * inv);
  *(bf16x4*)(obase) = ov;
#pragma unroll
  for (int r = 0; r < 4; ++r) ov[r] = (bf16_t)(acc1[r] * inv);
  *(bf16x4*)(obase + 16) = ov;
#pragma unroll
  for (int r = 0; r < 4; ++r) ov[r] = (bf16_t)(acc2[r] * inv);
  *(bf16x4*)(obase + 32) = ov;
#pragma unroll
  for (int r = 0; r < 4; ++r) ov[r] = (bf16_t)(acc3[r] * inv);
  *(bf16x4*)(obase + 48) = ov;
}

extern "C" void kernel_launch(void* const* d_in, const int* in_sizes, int n_in, void* d_out,
                              int out_size, void* d_ws, size_t ws_size, hipStream_t stream) {
  (void)in_sizes;
  (void)n_in;
  (void)out_size;
  (void)ws_size;
  const float* x = (const float*)d_in[0];
  const float* wq = (const float*)d_in[1];
  const float* wk = (const float*)d_in[2];
  const float* wv = (const float*)d_in[3];
  const float* wo = (const float*)d_in[4];
  const float* fcos = (const float*)d_in[5];
  const float* fsin = (const float*)d_in[6];
  float* out = (float*)d_out;

  bf16_t* xb = (bf16_t*)d_ws;
  bf16_t* wt = xb + (size_t)2048 * 2048;
  bf16_t* qbuf = wt + (size_t)5120 * 2048;
  bf16_t* kbuf = qbuf + (size_t)2048 * 2048;
  bf16_t* vtb = kbuf + (size_t)2048 * 512;
  bf16_t* att = vtb + (size_t)512 * 2048;

  cvt_k<<<2048, 256, 0, stream>>>(x, xb, 2048 * 2048);
  tr_k<<<dim3(32, 32), 256, 0, stream>>>(wq, 2048, wt);
  tr_k<<<dim3(8, 32), 256, 0, stream>>>(wk, 512, wt + (size_t)2048 * 2048);
  tr_k<<<dim3(8, 32), 256, 0, stream>>>(wv, 512, wt + (size_t)2560 * 2048);
  tr_k<<<dim3(32, 32), 256, 0, stream>>>(wo, 2048, wt + (size_t)3072 * 2048);
  gemm_k<0><<<dim3(24, 16), 256, 0, stream>>>(xb, wt, qbuf, kbuf, vtb, nullptr, fcos, fsin);
  attn_k<<<dim3(32, 32), 256, 0, stream>>>(qbuf, kbuf, vtb, att);
  gemm_k<1><<<dim3(16, 16), 256, 0, stream>>>(att, wt + (size_t)3072 * 2048, nullptr, nullptr,
                                              nullptr, out, fcos, fsin);
}

// Round 6
// 214.773 us; speedup vs baseline: 1.5952x; 1.1950x over previous
//
#include <hip/hip_runtime.h>
#include <stdint.h>

typedef __bf16 bf16_t;
typedef __bf16 bf16x8 __attribute__((ext_vector_type(8)));
typedef __bf16 bf16x4 __attribute__((ext_vector_type(4)));
typedef float floatx4 __attribute__((ext_vector_type(4)));

#define AS3(p) ((__attribute__((address_space(3))) void*)(p))
#define AS1(p) ((__attribute__((address_space(1))) void*)(void*)(p))

// ---------- convert f32 -> bf16, flat ----------
__global__ __launch_bounds__(256) void cvt_k(const float* __restrict__ src,
                                             bf16_t* __restrict__ dst, int n) {
  const int i = (blockIdx.x * 256 + threadIdx.x) * 8;
  if (i + 8 <= n) {
    floatx4 a = *(const floatx4*)&src[i];
    floatx4 b = *(const floatx4*)&src[i + 4];
    bf16x8 o;
#pragma unroll
    for (int j = 0; j < 4; ++j) { o[j] = (bf16_t)a[j]; o[4 + j] = (bf16_t)b[j]; }
    *(bf16x8*)&dst[i] = o;
  }
}

// ---------- transpose + convert: dst[n][k] = (bf16)src[k][n]; src f32 [2048][ncols] ----------
__global__ __launch_bounds__(256) void tr_k(const float* __restrict__ src, int ncols,
                                            bf16_t* __restrict__ dst) {
  __shared__ __align__(16) bf16_t T[64][68];
  const int t = threadIdx.x;
  const int nt = blockIdx.x * 64, kt = blockIdx.y * 64;
  const int r0 = t >> 4;          // 0..15
  const int c0 = (t & 15) << 2;   // 0..60
#pragma unroll
  for (int p = 0; p < 4; ++p) {
    const int row = p * 16 + r0;
    floatx4 v = *(const floatx4*)&src[(size_t)(kt + row) * ncols + nt + c0];
    bf16x4 b;
#pragma unroll
    for (int i = 0; i < 4; ++i) b[i] = (bf16_t)v[i];
    *(bf16x4*)&T[row][c0] = b;
  }
  __syncthreads();
#pragma unroll
  for (int p = 0; p < 4; ++p) {
    const int n = p * 16 + r0;
    bf16x4 tmp;
#pragma unroll
    for (int i = 0; i < 4; ++i) tmp[i] = T[c0 + i][n];
    *(bf16x4*)&dst[(size_t)(nt + n) * 2048 + kt + c0] = tmp;
  }
}

// ---------- GEMM: C[m][n] = sum_k A[m][k] * Bt[n][k], K=2048, A/Bt bf16 ----------
// Tile 64(M) x 128(N), BK=64, 4 waves (wave = 64x32). Grid is a multiple of
// 256 blocks (3/CU for QKV, 2/CU for out) — fixes R5's 13.5% occupancy.
// LDS chunk-swizzle (slot c^(r&7)): implemented by permuting the *global
// source* chunk per lane (global_load_lds LDS side is fixed base+lane*16).
// Kills R5's 9.4M bank-conflict cycles; read offset is a per-lane constant.
template <int EPI>
__global__ __launch_bounds__(256) void gemm_k(const bf16_t* __restrict__ A,
                                              const bf16_t* __restrict__ Bt,
                                              bf16_t* __restrict__ o0,
                                              bf16_t* __restrict__ o1,
                                              bf16_t* __restrict__ o2,
                                              float* __restrict__ fo,
                                              const float* __restrict__ fcos,
                                              const float* __restrict__ fsin) {
  constexpr int K = 2048;
  __shared__ __align__(16) bf16_t As[64 * 64];
  __shared__ __align__(16) bf16_t Bs[128 * 64];
  const int tid = threadIdx.x;
  const int lane = tid & 63;
  const int w = tid >> 6;
  const int quad = lane >> 4;
  const int l15 = lane & 15;
  const int m0 = blockIdx.y * 64;
  const int n0 = blockIdx.x * 128;
  // staging: lane covers row (base + lane>>3), swizzled chunk (lane&7)^((lane>>3)&7)
  const int sr = lane >> 3;
  const int sc = ((lane & 7) ^ (sr & 7)) << 3;
  const bf16_t* gA = A + (size_t)(m0 + w * 16 + sr) * K + sc;   // A instrs j=2w,2w+1
  const bf16_t* gB = Bt + (size_t)(n0 + w * 32 + sr) * K + sc;  // B instrs j=4w..4w+3
  bf16_t* lA = &As[w * 1024];
  bf16_t* lB = &Bs[w * 2048];
  floatx4 acc[4][2] = {};

  for (int k0 = 0; k0 < K; k0 += 64) {
    __builtin_amdgcn_global_load_lds(AS1(gA + k0), AS3(lA), 16, 0, 0);
    __builtin_amdgcn_global_load_lds(AS1(gA + 8 * K + k0), AS3(lA + 512), 16, 0, 0);
#pragma unroll
    for (int qq = 0; qq < 4; ++qq)
      __builtin_amdgcn_global_load_lds(AS1(gB + (size_t)qq * 8 * K + k0),
                                       AS3(lB + qq * 512), 16, 0, 0);
    __syncthreads();
#pragma unroll
    for (int kk = 0; kk < 2; ++kk) {
      const int co = ((kk * 4 + quad) ^ (l15 & 7)) << 3;  // per-lane const offset
      bf16x8 af[4], bfr[2];
#pragma unroll
      for (int i = 0; i < 4; ++i) af[i] = *(const bf16x8*)&As[(i * 16 + l15) * 64 + co];
#pragma unroll
      for (int i = 0; i < 2; ++i)
        bfr[i] = *(const bf16x8*)&Bs[(w * 32 + i * 16 + l15) * 64 + co];
#pragma unroll
      for (int mi = 0; mi < 4; ++mi)
#pragma unroll
        for (int ni = 0; ni < 2; ++ni)
          acc[mi][ni] =
              __builtin_amdgcn_mfma_f32_16x16x32_bf16(af[mi], bfr[ni], acc[mi][ni], 0, 0, 0);
    }
    __syncthreads();
  }

  if constexpr (EPI == 0) {
#pragma unroll
    for (int ni = 0; ni < 2; ++ni) {
      const int col = n0 + w * 32 + ni * 16 + l15;
#pragma unroll
      for (int mi = 0; mi < 4; ++mi) {
        const int sb = m0 + mi * 16 + quad * 4;
        if (col < 2560) {  // uniform per wave (boundaries are multiples of 16)
          const int fi = (col & 63) >> 1;
#pragma unroll
          for (int r = 0; r < 4; ++r) {
            const float v = acc[mi][ni][r];
            const float prt = __shfl_xor(v, 1);  // partner column within rope pair
            const int s = sb + r;
            const float c = fcos[s * 32 + fi];
            const float sn = fsin[s * 32 + fi];
            const float ov = (col & 1) ? (prt * sn + v * c) : (v * c - prt * sn);
            if (col < 2048)
              o0[(size_t)s * 2048 + col] = (bf16_t)ov;
            else
              o1[(size_t)s * 512 + (col - 2048)] = (bf16_t)ov;
          }
        } else {
          // sigma permutation within the 32-aligned s-block:
          // logical (t=mi&1, qs=quad, r) -> storage quad*8 + (mi&1)*4 + r
          const int sp = (sb & ~31) | (quad * 8 + (mi & 1) * 4);
          bf16x4 pv;
#pragma unroll
          for (int r = 0; r < 4; ++r) pv[r] = (bf16_t)acc[mi][ni][r];
          *(bf16x4*)&o2[(size_t)(col - 2560) * 2048 + sp] = pv;
        }
      }
    }
  } else {
#pragma unroll
    for (int ni = 0; ni < 2; ++ni) {
      const int col = n0 + w * 32 + ni * 16 + l15;
#pragma unroll
      for (int mi = 0; mi < 4; ++mi) {
        const int sb = m0 + mi * 16 + quad * 4;
#pragma unroll
        for (int r = 0; r < 4; ++r) fo[(size_t)(sb + r) * 2048 + col] = acc[mi][ni][r];
      }
    }
  }
}

// ---------- flash attention, S^T formulation, LDS-staged K/V (unchanged from R5) ----------
__global__ __launch_bounds__(256) void attn_k(const bf16_t* __restrict__ qb_,
                                              const bf16_t* __restrict__ kb_,
                                              const bf16_t* __restrict__ vt_,
                                              bf16_t* __restrict__ ob_) {
  __shared__ __align__(16) bf16_t sm[2][8 * 512];
  const int lane = threadIdx.x & 63, w = threadIdx.x >> 6;
  const int quad = lane >> 4, l15 = lane & 15;
  const int h = blockIdx.y, g = h >> 2;
  const int qb = (gridDim.x - 1 - blockIdx.x) * 64;  // heavy blocks first
  const int qw = qb + w * 16;
  const int q = qw + l15;
  const bf16_t* qrow = qb_ + (size_t)q * 2048 + h * 64;
  const bf16x8 qf0 = *(const bf16x8*)(qrow + quad * 8);
  const bf16x8 qf1 = *(const bf16x8*)(qrow + 32 + quad * 8);
  floatx4 acc0 = {}, acc1 = {}, acc2 = {}, acc3 = {}, accl = {};
  const float SC = 0.125f * 1.44269504088896340736f;  // scale * log2(e)
  bf16x8 ones;
#pragma unroll
  for (int i = 0; i < 8; ++i) ones[i] = (bf16_t)1.0f;

  int kbB = qb - 1024;
  if (kbB < 0) kbB = 0;
  kbB &= ~31;
  const int nT = (qb + 64 - kbB) >> 5;  // block-level tile count
  int myS = qw - 1024;
  if (myS < 0) myS = 0;
  myS &= ~31;
  const int myE = qw + 16;

  const int lr = lane & 15, lc = lane >> 4;
  const bf16_t* gk = kb_ + (size_t)(kbB + (w >> 1) * 16 + lr) * 512 + g * 64 +
                     ((w & 1) * 4 + lc) * 8;
  const bf16_t* gv = vt_ + (size_t)(g * 64 + w * 16 + lr) * 2048 + kbB + lc * 8;

#define STAGE(bi, ti)                                                              \
  do {                                                                             \
    __builtin_amdgcn_global_load_lds(AS1(gk + (size_t)(ti) * (32 * 512)),          \
                                     AS3(&sm[bi][w * 512]), 16, 0, 0);             \
    __builtin_amdgcn_global_load_lds(AS1(gv + (size_t)(ti) * 32),                  \
                                     AS3(&sm[bi][(4 + w) * 512]), 16, 0, 0);       \
  } while (0)

#define MSK(pv, key)                                        \
  do {                                                      \
    if ((key) > q || (key) + 1024 < q) pv = -1.0e30f;       \
  } while (0)

  int kb = kbB;
  STAGE(0, 0);
  __syncthreads();
  for (int i = 0; i < nT; ++i, kb += 32) {
    if (i + 1 < nT) STAGE((i + 1) & 1, i + 1);
    if (kb >= myS && kb < myE) {  // wave-uniform
      const bf16_t* base = &sm[i & 1][(size_t)lane * 8];
      const bf16x8 k0 = *(const bf16x8*)(base);
      const bf16x8 k1 = *(const bf16x8*)(base + 512);
      const bf16x8 k2 = *(const bf16x8*)(base + 1024);
      const bf16x8 k3 = *(const bf16x8*)(base + 1536);
      const bf16x8 v0 = *(const bf16x8*)(base + 2048);
      const bf16x8 v1 = *(const bf16x8*)(base + 2560);
      const bf16x8 v2 = *(const bf16x8*)(base + 3072);
      const bf16x8 v3 = *(const bf16x8*)(base + 3584);
      floatx4 z0 = {}, z1 = {};
      z0 = __builtin_amdgcn_mfma_f32_16x16x32_bf16(k0, qf0, z0, 0, 0, 0);
      z0 = __builtin_amdgcn_mfma_f32_16x16x32_bf16(k1, qf1, z0, 0, 0, 0);
      z1 = __builtin_amdgcn_mfma_f32_16x16x32_bf16(k2, qf0, z1, 0, 0, 0);
      z1 = __builtin_amdgcn_mfma_f32_16x16x32_bf16(k3, qf1, z1, 0, 0, 0);
      float p0 = z0[0] * SC - 32.0f, p1 = z0[1] * SC - 32.0f;
      float p2 = z0[2] * SC - 32.0f, p3 = z0[3] * SC - 32.0f;
      float p4 = z1[0] * SC - 32.0f, p5 = z1[1] * SC - 32.0f;
      float p6 = z1[2] * SC - 32.0f, p7 = z1[3] * SC - 32.0f;
      if ((kb + 31 > qw) || (kb < qw - 1009)) {  // wave-uniform edge mask
        const int kq = kb + quad * 4;
        MSK(p0, kq + 0); MSK(p1, kq + 1); MSK(p2, kq + 2); MSK(p3, kq + 3);
        MSK(p4, kq + 16); MSK(p5, kq + 17); MSK(p6, kq + 18); MSK(p7, kq + 19);
      }
      bf16x8 pf;  // == P^T B-fragment directly (sigma-permuted V columns)
      pf[0] = (bf16_t)__builtin_amdgcn_exp2f(p0);
      pf[1] = (bf16_t)__builtin_amdgcn_exp2f(p1);
      pf[2] = (bf16_t)__builtin_amdgcn_exp2f(p2);
      pf[3] = (bf16_t)__builtin_amdgcn_exp2f(p3);
      pf[4] = (bf16_t)__builtin_amdgcn_exp2f(p4);
      pf[5] = (bf16_t)__builtin_amdgcn_exp2f(p5);
      pf[6] = (bf16_t)__builtin_amdgcn_exp2f(p6);
      pf[7] = (bf16_t)__builtin_amdgcn_exp2f(p7);
      accl = __builtin_amdgcn_mfma_f32_16x16x32_bf16(ones, pf, accl, 0, 0, 0);
      acc0 = __builtin_amdgcn_mfma_f32_16x16x32_bf16(v0, pf, acc0, 0, 0, 0);
      acc1 = __builtin_amdgcn_mfma_f32_16x16x32_bf16(v1, pf, acc1, 0, 0, 0);
      acc2 = __builtin_amdgcn_mfma_f32_16x16x32_bf16(v2, pf, acc2, 0, 0, 0);
      acc3 = __builtin_amdgcn_mfma_f32_16x16x32_bf16(v3, pf, acc3, 0, 0, 0);
    }
    __syncthreads();
  }
#undef STAGE
#undef MSK

  const float inv = 1.0f / accl[0];
  bf16_t* obase = ob_ + (size_t)q * 2048 + h * 64 + quad * 4;
  bf16x4 ov;
#pragma unroll
  for (int r = 0; r < 4; ++r) ov[r] = (bf16_t)(acc0[r] * inv);
  *(bf16x4*)(obase) = ov;
#pragma unroll
  for (int r = 0; r < 4; ++r) ov[r] = (bf16_t)(acc1[r] * inv);
  *(bf16x4*)(obase + 16) = ov;
#pragma unroll
  for (int r = 0; r < 4; ++r) ov[r] = (bf16_t)(acc2[r] * inv);
  *(bf16x4*)(obase + 32) = ov;
#pragma unroll
  for (int r = 0; r < 4; ++r) ov[r] = (bf16_t)(acc3[r] * inv);
  *(bf16x4*)(obase + 48) = ov;
}

extern "C" void kernel_launch(void* const* d_in, const int* in_sizes, int n_in, void* d_out,
                              int out_size, void* d_ws, size_t ws_size, hipStream_t stream) {
  (void)in_sizes;
  (void)n_in;
  (void)out_size;
  (void)ws_size;
  const float* x = (const float*)d_in[0];
  const float* wq = (const float*)d_in[1];
  const float* wk = (const float*)d_in[2];
  const float* wv = (const float*)d_in[3];
  const float* wo = (const float*)d_in[4];
  const float* fcos = (const float*)d_in[5];
  const float* fsin = (const float*)d_in[6];
  float* out = (float*)d_out;

  bf16_t* xb = (bf16_t*)d_ws;
  bf16_t* wt = xb + (size_t)2048 * 2048;
  bf16_t* qbuf = wt + (size_t)5120 * 2048;
  bf16_t* kbuf = qbuf + (size_t)2048 * 2048;
  bf16_t* vtb = kbuf + (size_t)2048 * 512;
  bf16_t* att = vtb + (size_t)512 * 2048;

  cvt_k<<<2048, 256, 0, stream>>>(x, xb, 2048 * 2048);
  tr_k<<<dim3(32, 32), 256, 0, stream>>>(wq, 2048, wt);
  tr_k<<<dim3(8, 32), 256, 0, stream>>>(wk, 512, wt + (size_t)2048 * 2048);
  tr_k<<<dim3(8, 32), 256, 0, stream>>>(wv, 512, wt + (size_t)2560 * 2048);
  tr_k<<<dim3(32, 32), 256, 0, stream>>>(wo, 2048, wt + (size_t)3072 * 2048);
  gemm_k<0><<<dim3(24, 32), 256, 0, stream>>>(xb, wt, qbuf, kbuf, vtb, nullptr, fcos, fsin);
  attn_k<<<dim3(32, 32), 256, 0, stream>>>(qbuf, kbuf, vtb, att);
  gemm_k<1><<<dim3(16, 32), 256, 0, stream>>>(att, wt + (size_t)3072 * 2048, nullptr, nullptr,
                                              nullptr, out, fcos, fsin);
}